// Round 2
// baseline (1530.860 us; speedup 1.0000x reference)
//
#include <hip/hip_runtime.h>
#include <hip/hip_fp16.h>
#include <cstdint>
#include <cstddef>

#define Bn 4
#define Hn 16
#define Sn 2048
#define Dn 128
#define BHn (Bn*Hn)

typedef _Float16 half8  __attribute__((ext_vector_type(8)));
typedef _Float16 half2v __attribute__((ext_vector_type(2)));
typedef float    f32x16 __attribute__((ext_vector_type(16)));
typedef unsigned uint4v __attribute__((ext_vector_type(4)));

__device__ __forceinline__ int pk_f16(float a, float b){
  auto h = __builtin_amdgcn_cvt_pkrtz(a, b);   // __fp16x2 on gfx950
  return __builtin_bit_cast(int, h);
}

// ---------------- prep kernels ----------------

__global__ void k_rope_table(float2* __restrict__ tab){
  const int idx = blockIdx.x*256 + threadIdx.x;     // [s][i], 2048*64
  const int i = idx & 63, s = idx >> 6;
  const double invf = exp(-(double)i * (9.210340371976184 / 64.0)); // 10000^(-i/64)
  const double ang  = (double)s * invf;
  float2 cs; cs.x = (float)cos(ang); cs.y = (float)sin(ang);
  tab[idx] = cs;
}

__global__ void k_rope_apply(const float* __restrict__ q, const float* __restrict__ k,
                             const float2* __restrict__ tab,
                             half2v* __restrict__ qh, half2v* __restrict__ kh){
  const int idx = blockIdx.x*256 + threadIdx.x;     // 8388608 pairs
  const int d2 = idx & 63;
  const int s  = (idx >> 6) & (Sn-1);
  const float2 cs = tab[(s<<6) + d2];
  const float2 xq = ((const float2*)q)[idx];
  const float2 xk = ((const float2*)k)[idx];
  const float SC = 0.08838834764831845f;            // 1/sqrt(128), folded into q
  const float q0 = (xq.x*cs.x - xq.y*cs.y) * SC;
  const float q1 = (xq.y*cs.x + xq.x*cs.y) * SC;
  const float k0 =  xk.x*cs.x - xk.y*cs.y;
  const float k1 =  xk.y*cs.x + xk.x*cs.y;
  half2v hq = { (_Float16)q0, (_Float16)q1 };
  half2v hk = { (_Float16)k0, (_Float16)k1 };
  qh[idx] = hq;
  kh[idx] = hk;
}

__global__ void k_vtrans(const float* __restrict__ v, _Float16* __restrict__ vt){
  __shared__ float tile[32][33];
  const int bid = blockIdx.x;                       // BH*64*4
  const int dt = bid & 3, st = (bid >> 2) & 63, bh = bid >> 8;
  const int r = threadIdx.x >> 5, c = threadIdx.x & 31;
#pragma unroll
  for (int j = 0; j < 4; ++j){
    const int row = r + j*8;
    tile[row][c] = v[((size_t)bh*Sn + st*32 + row)*Dn + dt*32 + c];
  }
  __syncthreads();
#pragma unroll
  for (int j = 0; j < 4; ++j){
    const int row = r + j*8;
    vt[((size_t)bh*Dn + dt*32 + row)*Sn + st*32 + c] = (_Float16)tile[c][row];
  }
}

__global__ void k_maskbits(const int* __restrict__ mask, unsigned* __restrict__ mtb){
  const int g = blockIdx.x*256 + threadIdx.x;       // [q32][k], 64*2048
  const int k = g & (Sn-1), q32 = g >> 11;
  unsigned bits = 0u;
  for (int j = 0; j < 32; ++j)
    bits |= (mask[(size_t)(q32*32 + j)*Sn + k] != 0 ? 1u : 0u) << j;
  mtb[g] = bits;
}

// ---------------- main attention kernel ----------------
// grid 4096 = BH * (S/32); block 512 = 8 waves.
// Per block: 32 q-rows. Per wave: 256 k-cols. Swapped QK^T: acc = S^T tiles,
// lane holds S[q = l&31][k = kt*32 + (r&3) + 8*(r>>2) + 4*(l>>5)] (q fixed per lane).

__global__ __launch_bounds__(512, 2) void attn_main(
    const _Float16* __restrict__ qh, const _Float16* __restrict__ kh,
    const _Float16* __restrict__ vt, const unsigned* __restrict__ mtb,
    float* __restrict__ out, float* __restrict__ pout)
{
  __shared__ float lds_out[128*33];
  __shared__ float redA[256];
  __shared__ float redB[256];

  const int bid  = blockIdx.x;
  const int work = ((bid & 7) << 9) + (bid >> 3);   // XCD-contiguous bh ranges
  const int bh   = work >> 6;
  const int qb   = work & 63;
  const int tid  = threadIdx.x;
  const int w    = tid >> 6;
  const int l    = tid & 63;
  const int ln   = l & 31;
  const int h    = l >> 5;
  const int kbase = w << 8;
  const int qbase = qb << 5;

  for (int i = tid; i < 128*33; i += 512) lds_out[i] = 0.f;

  const size_t bQK = (size_t)bh * (Sn*Dn);

  // Q fragments (B-operand): lane holds Q[qbase+ln][dc*16 + h*8 + j]
  const half8* qrow = (const half8*)(qh + bQK + (size_t)(qbase + ln)*Dn + h*8);
  half8 qf[8];
#pragma unroll
  for (int dc = 0; dc < 8; ++dc) qf[dc] = qrow[dc*2];

  // ---- QK^T (swapped: A = K tile, B = Q) ----
  f32x16 acc[8];
  const _Float16* kbp = kh + bQK + (size_t)(kbase + ln)*Dn + h*8;
#pragma unroll
  for (int kt = 0; kt < 8; ++kt){
    const half8* krow = (const half8*)(kbp + (size_t)kt*32*Dn);
    f32x16 a;
#pragma unroll
    for (int i = 0; i < 16; ++i) a[i] = 0.f;
#pragma unroll
    for (int dc = 0; dc < 8; ++dc)
      a = __builtin_amdgcn_mfma_f32_32x32x16_f16(krow[dc*2], qf[dc], a, 0, 0, 0);
    acc[kt] = a;
  }

  // ---- mask + per-lane (= per-q-row-slice) max ----
  float m = -3.0e38f;
  const unsigned* mrow = mtb + (size_t)qb*Sn + kbase;
#pragma unroll
  for (int kt = 0; kt < 8; ++kt){
#pragma unroll
    for (int mm = 0; mm < 4; ++mm){
      const uint4v dw = *(const uint4v*)(mrow + kt*32 + mm*8 + h*4);
#pragma unroll
      for (int a = 0; a < 4; ++a){
        const int r = mm*4 + a;
        float s = acc[kt][r];
        s = ((dw[a] >> ln) & 1u) ? s : -1.0e30f;
        acc[kt][r] = s;
        m = fmaxf(m, s);
      }
    }
  }
  m = fmaxf(m, __shfl_xor(m, 32, 64));
  if (l < 32) redA[(w<<5) + ln] = m;
  __syncthreads();
  float mf = -3.0e38f;
#pragma unroll
  for (int ww = 0; ww < 8; ++ww) mf = fmaxf(mf, redA[(ww<<5) + ln]);

  // ---- exp + row sum ----
  float lsum = 0.f;
#pragma unroll
  for (int kt = 0; kt < 8; ++kt){
#pragma unroll
    for (int r = 0; r < 16; ++r){
      const float e = __expf(acc[kt][r] - mf);
      acc[kt][r] = e;
      lsum += e;
    }
  }
  lsum += __shfl_xor(lsum, 32, 64);
  if (l < 32) redB[(w<<5) + ln] = lsum;
  __syncthreads();
  float Lr = 0.f;
#pragma unroll
  for (int ww = 0; ww < 8; ++ww) Lr += redB[(ww<<5) + ln];
  const float rinv = 1.0f / Lr;

  // ---- normalize, store p_attn (float4), pack fp16 for PV ----
  float* prow = pout + ((size_t)bh*Sn + qbase + ln)*Sn + kbase;
  int pk[8][8];
#pragma unroll
  for (int kt = 0; kt < 8; ++kt){
#pragma unroll
    for (int r = 0; r < 16; ++r) acc[kt][r] *= rinv;
#pragma unroll
    for (int t = 0; t < 2; ++t){
#pragma unroll
      for (int b2 = 0; b2 < 2; ++b2){
        const int g = (t<<1) + b2;     // acc group: r = a + 4*(b2 + 2t)
        float4 v4 = make_float4(acc[kt][4*g+0], acc[kt][4*g+1],
                                acc[kt][4*g+2], acc[kt][4*g+3]);
        *(float4*)(prow + kt*32 + t*16 + b2*8 + h*4) = v4;
        pk[kt][((t<<1)+b2)*2 + 0] = pk_f16(acc[kt][4*g+0], acc[kt][4*g+1]);
        pk[kt][((t<<1)+b2)*2 + 1] = pk_f16(acc[kt][4*g+2], acc[kt][4*g+3]);
      }
    }
  }

  // ---- PV: out^T = V^T (A) x P^T (B), B built by half-swap of packed p ----
  f32x16 oacc[4];
#pragma unroll
  for (int dt = 0; dt < 4; ++dt)
#pragma unroll
    for (int i = 0; i < 16; ++i) oacc[dt][i] = 0.f;

  const _Float16* vbp = vt + (size_t)bh*(Dn*Sn) + (size_t)ln*Sn + kbase + h*8;
#pragma unroll
  for (int kt = 0; kt < 8; ++kt){
#pragma unroll
    for (int t = 0; t < 2; ++t){
      const int P00 = pk[kt][((t<<1)+0)*2+0];
      const int P01 = pk[kt][((t<<1)+0)*2+1];
      const int P10 = pk[kt][((t<<1)+1)*2+0];
      const int P11 = pk[kt][((t<<1)+1)*2+1];
      const int S00 = __shfl_xor(P00, 32, 64);
      const int S01 = __shfl_xor(P01, 32, 64);
      const int S10 = __shfl_xor(P10, 32, 64);
      const int S11 = __shfl_xor(P11, 32, 64);
      int4 bi;
      bi.x = h ? S10 : P00;
      bi.y = h ? S11 : P01;
      bi.z = h ? P10 : S00;
      bi.w = h ? P11 : S01;
      const half8 bf = __builtin_bit_cast(half8, bi);
      const int c16 = kt*32 + t*16;
#pragma unroll
      for (int dt = 0; dt < 4; ++dt){
        const half8 af = *(const half8*)(vbp + (size_t)dt*32*Sn + c16);
        oacc[dt] = __builtin_amdgcn_mfma_f32_32x32x16_f16(af, bf, oacc[dt], 0, 0, 0);
      }
    }
  }

  // ---- cross-wave reduce out^T in LDS, then coalesced store ----
#pragma unroll
  for (int dt = 0; dt < 4; ++dt){
#pragma unroll
    for (int r = 0; r < 16; ++r){
      const int d = dt*32 + (r&3) + 8*(r>>2) + h*4;
      atomicAdd(&lds_out[d*33 + ln], oacc[dt][r]);
    }
  }
  __syncthreads();
  const size_t obase = ((size_t)bh*Sn + qbase)*Dn;
  for (int i = tid; i < 32*128; i += 512){
    const int qq = i >> 7, dd = i & 127;
    out[obase + (size_t)qq*Dn + dd] = lds_out[dd*33 + qq];
  }
}

// ---------------- launch ----------------

extern "C" void kernel_launch(void* const* d_in, const int* in_sizes, int n_in,
                              void* d_out, int out_size, void* d_ws, size_t ws_size,
                              hipStream_t stream)
{
  const float* dq = (const float*)d_in[0];
  const float* dk = (const float*)d_in[1];
  const float* dv = (const float*)d_in[2];
  const int*   dm = (const int*)d_in[3];

  char* ws = (char*)d_ws;
  float2*   tab = (float2*)ws;                                  // 1 MiB
  _Float16* qh  = (_Float16*)(ws + (size_t)(1u<<20));           // 32 MiB
  _Float16* kh  = (_Float16*)(ws + (size_t)(1u<<20) + ((size_t)32<<20));
  _Float16* vtp = (_Float16*)(ws + (size_t)(1u<<20) + ((size_t)64<<20));
  unsigned* mtb = (unsigned*)(ws + (size_t)(1u<<20) + ((size_t)96<<20));

  float* out  = (float*)d_out;
  float* pout = out + (size_t)Bn*Hn*Sn*Dn;

  k_rope_table<<<512,   256, 0, stream>>>(tab);
  k_rope_apply<<<32768, 256, 0, stream>>>(dq, dk, tab, (half2v*)qh, (half2v*)kh);
  k_vtrans    <<<16384, 256, 0, stream>>>(dv, vtp);
  k_maskbits  <<<512,   256, 0, stream>>>(dm, mtb);
  attn_main   <<<4096,  512, 0, stream>>>(qh, kh, vtp, mtb, out, pout);
}

// Round 3
// 1170.392 us; speedup vs baseline: 1.3080x; 1.3080x over previous
//
#include <hip/hip_runtime.h>
#include <hip/hip_fp16.h>
#include <cstdint>
#include <cstddef>

#define Bn 4
#define Hn 16
#define Sn 2048
#define Dn 128

typedef _Float16 half8  __attribute__((ext_vector_type(8)));
typedef float    f32x16 __attribute__((ext_vector_type(16)));
typedef unsigned uint4v __attribute__((ext_vector_type(4)));

__device__ __forceinline__ int pk_f16(float a, float b){
  auto h = __builtin_amdgcn_cvt_pkrtz(a, b);   // __fp16x2
  return __builtin_bit_cast(int, h);
}

// ---------------- prep kernels ----------------

__global__ void k_rope_table(float2* __restrict__ tab){
  const int idx = blockIdx.x*256 + threadIdx.x;     // [s][i], 2048*64
  const int i = idx & 63, s = idx >> 6;
  const double invf = exp(-(double)i * (9.210340371976184 / 64.0)); // 10000^(-i/64)
  const double ang  = (double)s * invf;
  float2 cs; cs.x = (float)cos(ang); cs.y = (float)sin(ang);
  tab[idx] = cs;
}

// Pack Q,K into MFMA-fragment order with rope applied.
// Chunk index t = ((bh*64 + blk)*8 + dc)*64 + lane; lane = ln + 32h holds
// row s = blk*32+ln, d-range dc*16 + h*8 .. +8  (8 halfs = 16B).
__global__ void k_pack_qk(const float* __restrict__ q, const float* __restrict__ k,
                          const float2* __restrict__ tab,
                          half8* __restrict__ qp, half8* __restrict__ kp){
  const int t    = blockIdx.x*256 + threadIdx.x;    // 2,097,152 chunks
  const int lane = t & 63, ln = lane & 31, h = lane >> 5;
  const int dc   = (t >> 6) & 7;
  const int blk  = (t >> 9) & 63;
  const int bh   = t >> 15;
  const int s    = blk*32 + ln;
  const size_t roff = ((size_t)bh*Sn + s)*Dn + dc*16 + h*8;
  const float4 a0 = *(const float4*)(q + roff);
  const float4 a1 = *(const float4*)(q + roff + 4);
  const float4 b0 = *(const float4*)(k + roff);
  const float4 b1 = *(const float4*)(k + roff + 4);
  const float2* tb = tab + s*64 + dc*8 + h*4;
  const float2 c0 = tb[0], c1 = tb[1], c2 = tb[2], c3 = tb[3];
  const float SC = 0.08838834764831845f;            // 1/sqrt(128) folded into q
  half8 qo, ko;
  qo[0] = (_Float16)((a0.x*c0.x - a0.y*c0.y)*SC);
  qo[1] = (_Float16)((a0.y*c0.x + a0.x*c0.y)*SC);
  qo[2] = (_Float16)((a0.z*c1.x - a0.w*c1.y)*SC);
  qo[3] = (_Float16)((a0.w*c1.x + a0.z*c1.y)*SC);
  qo[4] = (_Float16)((a1.x*c2.x - a1.y*c2.y)*SC);
  qo[5] = (_Float16)((a1.y*c2.x + a1.x*c2.y)*SC);
  qo[6] = (_Float16)((a1.z*c3.x - a1.w*c3.y)*SC);
  qo[7] = (_Float16)((a1.w*c3.x + a1.z*c3.y)*SC);
  ko[0] = (_Float16)(b0.x*c0.x - b0.y*c0.y);
  ko[1] = (_Float16)(b0.y*c0.x + b0.x*c0.y);
  ko[2] = (_Float16)(b0.z*c1.x - b0.w*c1.y);
  ko[3] = (_Float16)(b0.w*c1.x + b0.z*c1.y);
  ko[4] = (_Float16)(b1.x*c2.x - b1.y*c2.y);
  ko[5] = (_Float16)(b1.y*c2.x + b1.x*c2.y);
  ko[6] = (_Float16)(b1.z*c3.x - b1.w*c3.y);
  ko[7] = (_Float16)(b1.w*c3.x + b1.z*c3.y);
  qp[t] = qo;
  kp[t] = ko;
}

// Pack V^T into PV A-fragment order.
// Chunk t = ((bh*128 + k16)*4 + dt)*64 + lane; lane = ln+32h holds
// V[k16*16 + h*8 + j][dt*32 + ln], j = 0..7.
__global__ void k_pack_v(const float* __restrict__ v, half8* __restrict__ vp){
  const int t    = blockIdx.x*256 + threadIdx.x;    // 2,097,152 chunks
  const int lane = t & 63, ln = lane & 31, h = lane >> 5;
  const int dt   = (t >> 6) & 3;
  const int k16  = (t >> 8) & 127;
  const int bh   = t >> 15;
  const size_t base = ((size_t)bh*Sn + k16*16 + h*8)*Dn + dt*32 + ln;
  half8 o;
#pragma unroll
  for (int j = 0; j < 8; ++j) o[j] = (_Float16)v[base + (size_t)j*Dn];
  vp[t] = o;
}

__global__ void k_maskbits(const int* __restrict__ mask, unsigned* __restrict__ mtb){
  const int g = blockIdx.x*256 + threadIdx.x;       // [q32][k], 64*2048
  const int k = g & (Sn-1), q32 = g >> 11;
  unsigned bits = 0u;
  for (int j = 0; j < 32; ++j)
    bits |= (mask[(size_t)(q32*32 + j)*Sn + k] != 0 ? 1u : 0u) << j;
  mtb[g] = bits;
}

// ---------------- main attention kernel ----------------
// grid 4096 = BH * (S/32); block 512 = 8 waves. Per block: 32 q-rows.
// Per wave: 256 k-cols. Swapped QK^T (A=K, B=Q): lane holds
// S[q = ln][k = kt*32 + (r&3) + 8*(r>>2) + 4h]. All fragment loads coalesced
// from packed buffers; p stored via per-wave LDS transpose (full-line writes).

__global__ __launch_bounds__(512, 2) void attn_main(
    const half8* __restrict__ qp, const half8* __restrict__ kp,
    const half8* __restrict__ vp, const unsigned* __restrict__ mtb,
    float* __restrict__ out, float* __restrict__ pout)
{
  __shared__ float lds_out[128*33];
  __shared__ float redA[256];
  __shared__ float redB[256];
  __shared__ float pt[8][32][34];   // stride 34: float2-aligned, ~2-way banks

  const int bid  = blockIdx.x;
  const int work = ((bid & 7) << 9) + (bid >> 3);   // XCD-contiguous bh ranges
  const int bh   = work >> 6;
  const int qb   = work & 63;
  const int tid  = threadIdx.x;
  const int w    = tid >> 6;
  const int l    = tid & 63;
  const int ln   = l & 31;
  const int h    = l >> 5;
  const int kbase = w << 8;
  const int qbase = qb << 5;

  for (int i = tid; i < 128*33; i += 512) lds_out[i] = 0.f;

  // Q fragments (B-operand), coalesced
  half8 qf[8];
#pragma unroll
  for (int dc = 0; dc < 8; ++dc)
    qf[dc] = qp[((((size_t)bh*64 + qb)*8 + dc)*64) + l];

  // ---- QK^T ----
  f32x16 acc[8];
#pragma unroll
  for (int kt = 0; kt < 8; ++kt){
    const half8* kf = kp + (((size_t)bh*64 + (w*8 + kt))*8)*64 + l;
    f32x16 a;
#pragma unroll
    for (int i = 0; i < 16; ++i) a[i] = 0.f;
#pragma unroll
    for (int dc = 0; dc < 8; ++dc)
      a = __builtin_amdgcn_mfma_f32_32x32x16_f16(kf[(size_t)dc*64], qf[dc], a, 0, 0, 0);
    acc[kt] = a;
  }

  // ---- mask + per-lane max ----
  float m = -3.0e38f;
  const unsigned* mrow = mtb + (size_t)qb*Sn + kbase;
#pragma unroll
  for (int kt = 0; kt < 8; ++kt){
#pragma unroll
    for (int mm = 0; mm < 4; ++mm){
      const uint4v dw = *(const uint4v*)(mrow + kt*32 + mm*8 + h*4);
#pragma unroll
      for (int a = 0; a < 4; ++a){
        const int r = mm*4 + a;
        float s = acc[kt][r];
        s = ((dw[a] >> ln) & 1u) ? s : -1.0e30f;
        acc[kt][r] = s;
        m = fmaxf(m, s);
      }
    }
  }
  m = fmaxf(m, __shfl_xor(m, 32, 64));
  if (l < 32) redA[(w<<5) + ln] = m;
  __syncthreads();
  float mf = -3.0e38f;
#pragma unroll
  for (int ww = 0; ww < 8; ++ww) mf = fmaxf(mf, redA[(ww<<5) + ln]);

  // ---- exp + row sum ----
  float lsum = 0.f;
#pragma unroll
  for (int kt = 0; kt < 8; ++kt){
#pragma unroll
    for (int r = 0; r < 16; ++r){
      const float e = __expf(acc[kt][r] - mf);
      acc[kt][r] = e;
      lsum += e;
    }
  }
  lsum += __shfl_xor(lsum, 32, 64);
  if (l < 32) redB[(w<<5) + ln] = lsum;
  __syncthreads();
  float Lr = 0.f;
#pragma unroll
  for (int ww = 0; ww < 8; ++ww) Lr += redB[(ww<<5) + ln];
  const float rinv = 1.0f / Lr;

  // ---- fused per-kt: normalize -> LDS transpose -> store p -> PV MFMA ----
  f32x16 oacc[4];
#pragma unroll
  for (int dt = 0; dt < 4; ++dt)
#pragma unroll
    for (int i = 0; i < 16; ++i) oacc[dt][i] = 0.f;

  float* pbase = pout + ((size_t)bh*Sn + qbase)*Sn + kbase;
  const int rq = l >> 3;          // transposed-store: row within 8-row group
  const int rc = (l & 7) * 4;     // 4-float col offset

#pragma unroll
  for (int kt = 0; kt < 8; ++kt){
    // normalized scores -> pt[w][q=ln][k], k = g*8 + 4h + {0..3}
#pragma unroll
    for (int g = 0; g < 4; ++g){
      const int c = g*8 + h*4;
      float2 e0, e1;
      e0.x = acc[kt][4*g+0]*rinv; e0.y = acc[kt][4*g+1]*rinv;
      e1.x = acc[kt][4*g+2]*rinv; e1.y = acc[kt][4*g+3]*rinv;
      *(float2*)&pt[w][ln][c]   = e0;
      *(float2*)&pt[w][ln][c+2] = e1;
    }
    // transposed full-line store: lane -> row i*8+rq, cols kt*32+rc..+3
#pragma unroll
    for (int i = 0; i < 4; ++i){
      const int qq = i*8 + rq;
      const float2 t0 = *(const float2*)&pt[w][qq][rc];
      const float2 t1 = *(const float2*)&pt[w][qq][rc+2];
      float4 o4; o4.x = t0.x; o4.y = t0.y; o4.z = t1.x; o4.w = t1.y;
      *(float4*)(pbase + (size_t)qq*Sn + kt*32 + rc) = o4;
    }
    // PV: B-frag = P^T[k = t16*16 + h*8 + j][q = ln] from pt
#pragma unroll
    for (int t16 = 0; t16 < 2; ++t16){
      const int c = t16*16 + h*8;
      const float2 b0 = *(const float2*)&pt[w][ln][c];
      const float2 b1 = *(const float2*)&pt[w][ln][c+2];
      const float2 b2 = *(const float2*)&pt[w][ln][c+4];
      const float2 b3 = *(const float2*)&pt[w][ln][c+6];
      int4 bi;
      bi.x = pk_f16(b0.x, b0.y);
      bi.y = pk_f16(b1.x, b1.y);
      bi.z = pk_f16(b2.x, b2.y);
      bi.w = pk_f16(b3.x, b3.y);
      const half8 bf = __builtin_bit_cast(half8, bi);
      const half8* vf = vp + (((size_t)bh*128 + (w*16 + kt*2 + t16))*4)*64 + l;
#pragma unroll
      for (int dt = 0; dt < 4; ++dt)
        oacc[dt] = __builtin_amdgcn_mfma_f32_32x32x16_f16(vf[(size_t)dt*64], bf, oacc[dt], 0, 0, 0);
    }
  }

  // ---- cross-wave reduce out^T in LDS, then coalesced store ----
#pragma unroll
  for (int dt = 0; dt < 4; ++dt){
#pragma unroll
    for (int r = 0; r < 16; ++r){
      const int d = dt*32 + (r&3) + 8*(r>>2) + h*4;
      atomicAdd(&lds_out[d*33 + ln], oacc[dt][r]);
    }
  }
  __syncthreads();
  const size_t obase = ((size_t)bh*Sn + qbase)*Dn;
  for (int i = tid; i < 32*128; i += 512){
    const int qq = i >> 7, dd = i & 127;
    out[obase + (size_t)qq*Dn + dd] = lds_out[dd*33 + qq];
  }
}

// ---------------- launch ----------------

extern "C" void kernel_launch(void* const* d_in, const int* in_sizes, int n_in,
                              void* d_out, int out_size, void* d_ws, size_t ws_size,
                              hipStream_t stream)
{
  const float* dq = (const float*)d_in[0];
  const float* dk = (const float*)d_in[1];
  const float* dv = (const float*)d_in[2];
  const int*   dm = (const int*)d_in[3];

  char* ws = (char*)d_ws;
  float2*   tab = (float2*)ws;                                  // 1 MiB
  half8*    qp  = (half8*)(ws + (size_t)(1u<<20));              // 32 MiB
  half8*    kp  = (half8*)(ws + (size_t)(1u<<20) + ((size_t)32<<20));
  half8*    vp  = (half8*)(ws + (size_t)(1u<<20) + ((size_t)64<<20));
  unsigned* mtb = (unsigned*)(ws + (size_t)(1u<<20) + ((size_t)96<<20));

  float* out  = (float*)d_out;
  float* pout = out + (size_t)Bn*Hn*Sn*Dn;

  k_rope_table<<<512,  256, 0, stream>>>(tab);
  k_pack_qk   <<<8192, 256, 0, stream>>>(dq, dk, tab, qp, kp);
  k_pack_v    <<<8192, 256, 0, stream>>>(dv, vp);
  k_maskbits  <<<512,  256, 0, stream>>>(dm, mtb);
  attn_main   <<<4096, 512, 0, stream>>>(qp, kp, vp, mtb, out, pout);
}